// Round 11
// baseline (394.324 us; speedup 1.0000x reference)
//
#include <hip/hip_runtime.h>

typedef _Float16 half_t;
typedef __attribute__((ext_vector_type(8))) _Float16 half8;
typedef __attribute__((ext_vector_type(4))) _Float16 half4;
typedef __attribute__((ext_vector_type(4))) float float4v;

#define LN_EPS 1e-5f
#define QK_SCALE 0.17677669529663687f   // 32^-0.5

static __device__ __forceinline__ float4v mfma16(half8 a, half8 b, float4v c) {
    return __builtin_amdgcn_mfma_f32_16x16x32_f16(a, b, c, 0, 0, 0);
}

// 512B rows, XOR key (row>>1)&7
static __device__ __forceinline__ int swzA(int row, int colByte) {
    return row * 512 + ((((colByte >> 4) ^ ((row >> 1) & 7)) << 4) | (colByte & 15));
}
// 64B rows, XOR key (row>>1)&3
static __device__ __forceinline__ int swzB(int row, int colByte) {
    return row * 64 + ((((colByte >> 4) ^ ((row >> 1) & 3)) << 4) | (colByte & 15));
}
// 128B rows, XOR key row&7
static __device__ __forceinline__ int swzC(int row, int colByte) {
    return row * 128 + ((((colByte >> 4) ^ (row & 7)) << 4) | (colByte & 15));
}

static __device__ void ln_relu16(float* h, const float* __restrict__ g, const float* __restrict__ b) {
    float m = 0.f;
    for (int j = 0; j < 16; ++j) m += h[j];
    m *= (1.0f / 16.0f);
    float v = 0.f;
    for (int j = 0; j < 16; ++j) { float d = h[j] - m; v += d * d; }
    v *= (1.0f / 16.0f);
    float rs = rsqrtf(v + LN_EPS);
    for (int j = 0; j < 16; ++j) {
        float t = (h[j] - m) * rs * g[j] + b[j];
        h[j] = t > 0.f ? t : 0.f;
    }
}

// ---------------------------------------------------------------------------
// prep: weight transpose+fp16, pos-bias MLP, rel-bias table rbp[h][row][m][tj]
// ---------------------------------------------------------------------------
__global__ void prep_kernel(
    const float* __restrict__ qkv_w,   // [256,768]
    const float* __restrict__ proj_w,  // [256,256]
    const float* __restrict__ biases,  // [225,2]
    const float* __restrict__ pos_w, const float* __restrict__ pos_b,
    const float* __restrict__ ln1_g, const float* __restrict__ ln1_b,
    const float* __restrict__ fc1_w, const float* __restrict__ fc1_b,
    const float* __restrict__ ln2_g, const float* __restrict__ ln2_b,
    const float* __restrict__ fc2_w, const float* __restrict__ fc2_b,
    const float* __restrict__ ln3_g, const float* __restrict__ ln3_b,
    const float* __restrict__ fc3_w, const float* __restrict__ fc3_b,
    const int* __restrict__ rel_idx,   // [64,64]
    half_t* __restrict__ wqkvT,        // [768,256]
    half_t* __restrict__ wprojT,       // [256,256]
    float* __restrict__ rbp)           // [8][64][16][4]
{
    __shared__ float tile[64][65];
    __shared__ float pos_s[225][8];
    const int t = blockIdx.x;
    const int tid = threadIdx.x;

    if (t < 64) {
        const float* src; half_t* dst; int ncols, rg, cg;
        if (t < 48) { src = qkv_w;  dst = wqkvT;  ncols = 768; rg = t / 12;      cg = t % 12; }
        else        { src = proj_w; dst = wprojT; ncols = 256; rg = (t-48) >> 2; cg = (t-48) & 3; }
        const int r0 = tid >> 6, c = tid & 63;
        for (int i = 0; i < 16; ++i) {
            int r = i * 4 + r0;
            tile[r][c] = src[(rg * 64 + r) * ncols + cg * 64 + c];
        }
        __syncthreads();
        for (int i = 0; i < 16; ++i) {
            int r = i * 4 + r0;
            dst[(cg * 64 + r) * 256 + rg * 64 + c] = (half_t)tile[c][r];
        }
    } else {
        if (tid < 225) {
            float h[16], h2[16];
            float b0 = biases[tid * 2], b1 = biases[tid * 2 + 1];
            for (int j = 0; j < 16; ++j) h[j] = b0 * pos_w[j] + b1 * pos_w[16 + j] + pos_b[j];
            ln_relu16(h, ln1_g, ln1_b);
            for (int j = 0; j < 16; ++j) {
                float s = fc1_b[j];
                for (int k = 0; k < 16; ++k) s += h[k] * fc1_w[k * 16 + j];
                h2[j] = s;
            }
            ln_relu16(h2, ln2_g, ln2_b);
            for (int j = 0; j < 16; ++j) {
                float s = fc2_b[j];
                for (int k = 0; k < 16; ++k) s += h2[k] * fc2_w[k * 16 + j];
                h[j] = s;
            }
            ln_relu16(h, ln3_g, ln3_b);
            for (int j = 0; j < 8; ++j) {
                float s = fc3_b[j];
                for (int k = 0; k < 16; ++k) s += h[k] * fc3_w[k * 8 + j];
                pos_s[tid][j] = s;
            }
        }
        __syncthreads();
        for (int e = tid; e < 8 * 64 * 64; e += 256) {
            int hh = e >> 12, rem = e & 4095;
            int row = rem >> 6, c = rem & 63;
            int tj = c >> 4, mm = c & 15;
            rbp[hh * 4096 + row * 64 + mm * 4 + tj] = pos_s[rel_idx[row * 64 + c]][hh];
        }
    }
}

// ---------------------------------------------------------------------------
// K1: QKV GEMM per window. 256 thr = 4 waves; wave w owns col-tiles
// w*12..w*12+11 (pairs). Writes q,k ROW-MAJOR [win][64][256] fp16 (q_ws/k_ws
// live in d_out -- dead before proj overwrites) and v TRANSPOSED
// [win*8+h][32 d][64 n] fp16 into ws. Row-major q/k + vT make every K2 MFMA
// fragment a direct contiguous 16B load (no transposes downstream).
// State ~92 total regs -> (256,4) = 128 budget, 16 waves/CU.
// ---------------------------------------------------------------------------
__global__ __launch_bounds__(256, 4) void qkv_gemm_kernel(
    const float* __restrict__ x,
    const half_t* __restrict__ wqkvT,
    const float* __restrict__ qkv_b,
    half_t* __restrict__ q_ws,
    half_t* __restrict__ k_ws,
    half_t* __restrict__ vt_ws)
{
    __shared__ __align__(16) char smem[32768];
    char* xs = smem;
    const int win = blockIdx.x;
    const int tid = threadIdx.x;
    const int w = tid >> 6, lane = tid & 63, m = lane & 15, g = lane >> 4;

    const float* xg = x + (size_t)win * 16384;
    #pragma unroll
    for (int i = 0; i < 16; ++i) {
        int u = tid + i * 256;
        int row = u >> 6, c4 = u & 63;
        float4v xv = *(const float4v*)(xg + u * 4);
        half4 hv;
        hv[0] = (half_t)xv[0]; hv[1] = (half_t)xv[1];
        hv[2] = (half_t)xv[2]; hv[3] = (half_t)xv[3];
        *(half4*)(xs + swzA(row, c4 * 8)) = hv;
    }
    __syncthreads();

    #pragma unroll
    for (int p = 0; p < 6; ++p) {
        const int ct0 = w * 12 + p * 2;
        float4v acc[2][4];
        #pragma unroll
        for (int c2 = 0; c2 < 2; ++c2)
            #pragma unroll
            for (int ti = 0; ti < 4; ++ti) acc[c2][ti] = {0.f, 0.f, 0.f, 0.f};
        const half_t* wb = wqkvT + (size_t)(ct0 * 16 + m) * 256 + g * 8;
        #pragma unroll
        for (int kk = 0; kk < 8; ++kk) {
            half8 af[4];
            #pragma unroll
            for (int ti = 0; ti < 4; ++ti)
                af[ti] = *(const half8*)(xs + swzA(ti * 16 + m, kk * 64 + g * 16));
            half8 wf0 = *(const half8*)(wb + kk * 32);
            half8 wf1 = *(const half8*)(wb + 16 * 256 + kk * 32);
            #pragma unroll
            for (int ti = 0; ti < 4; ++ti) {
                acc[0][ti] = mfma16(af[ti], wf0, acc[0][ti]);   // A=x rows n, B=W cols
                acc[1][ti] = mfma16(af[ti], wf1, acc[1][ti]);
            }
        }
        #pragma unroll
        for (int c2 = 0; c2 < 2; ++c2) {
            const int ct = ct0 + c2;
            const float bias = qkv_b[ct * 16 + m];
            if (ct < 32) {                      // q (ct<16) or k
                half_t* dst = (ct < 16 ? q_ws : k_ws)
                              + (size_t)win * 16384 + (ct & 15) * 16 + m;
                #pragma unroll
                for (int ti = 0; ti < 4; ++ti)
                    #pragma unroll
                    for (int r = 0; r < 4; ++r)
                        dst[(size_t)(ti * 16 + g * 4 + r) * 256] =
                            (half_t)(acc[c2][ti][r] + bias);
            } else {                            // v -> vT [d][n]
                const int c = (ct - 32) * 16 + m;
                const int h = c >> 5, dm = c & 31;
                half_t* vd = vt_ws + ((size_t)(win * 8 + h) * 32 + dm) * 64;
                #pragma unroll
                for (int ti = 0; ti < 4; ++ti) {
                    half4 pk;
                    #pragma unroll
                    for (int r = 0; r < 4; ++r) pk[r] = (half_t)(acc[c2][ti][r] + bias);
                    *(half4*)(vd + ti * 16 + g * 4) = pk;
                }
            }
        }
    }
}

// ---------------------------------------------------------------------------
// K2: attention. 256 thr = 4 waves; block (win, half): wave = head
// (bb&1)*4+w. All fragments = direct contiguous 16B global loads (q,k
// row-major; v transposed). P goes through an 8KB wave-private LDS arena.
// ZERO __syncthreads. State ~110 -> (256,3) = 170 budget, 12 waves/CU.
// ---------------------------------------------------------------------------
__global__ __launch_bounds__(256, 3) void attn_kernel(
    const half_t* __restrict__ q_ws,
    const half_t* __restrict__ k_ws,
    const half_t* __restrict__ vt_ws,
    const float* __restrict__ rbp,
    half_t* __restrict__ attn_ws)
{
    __shared__ __align__(16) char smem[32768];
    const int bb = blockIdx.x, win = bb >> 1;
    const int tid = threadIdx.x;
    const int w = tid >> 6, lane = tid & 63, m = lane & 15, g = lane >> 4;
    const int h = (bb & 1) * 4 + w;
    char* wP = smem + w * 8192;        // P arena [64][128B], swzC

    // fragments: q rows -> A, k rows -> B (both contiguous)
    const half_t* qb_ = q_ws + (size_t)win * 16384 + h * 32 + g * 8;
    const half_t* kb_ = k_ws + (size_t)win * 16384 + h * 32 + g * 8;
    half8 aq[4], bk[4];
    #pragma unroll
    for (int t = 0; t < 4; ++t) {
        aq[t] = *(const half8*)(qb_ + (size_t)(t * 16 + m) * 256);
        bk[t] = *(const half8*)(kb_ + (size_t)(t * 16 + m) * 256);
    }

    // S + bias + softmax (no max-sub; P<=1), pre-normalized P -> arena
    const float* rbh = rbp + h * 4096;
    #pragma unroll
    for (int ti = 0; ti < 4; ++ti) {
        float4v z = {0.f, 0.f, 0.f, 0.f};
        float4v s0 = mfma16(aq[ti], bk[0], z);
        float4v s1 = mfma16(aq[ti], bk[1], z);
        float4v s2 = mfma16(aq[ti], bk[2], z);
        float4v s3 = mfma16(aq[ti], bk[3], z);
        #pragma unroll
        for (int r = 0; r < 4; ++r) {
            const int row = ti * 16 + g * 4 + r;
            float4v rb = *(const float4v*)(rbh + row * 64 + m * 4);
            float e0 = __expf(s0[r] * QK_SCALE + rb[0]);
            float e1 = __expf(s1[r] * QK_SCALE + rb[1]);
            float e2 = __expf(s2[r] * QK_SCALE + rb[2]);
            float e3 = __expf(s3[r] * QK_SCALE + rb[3]);
            float s = e0 + e1 + e2 + e3;
            s += __shfl_xor(s, 1); s += __shfl_xor(s, 2);
            s += __shfl_xor(s, 4); s += __shfl_xor(s, 8);
            float is = 1.0f / s;
            *(half_t*)(wP + swzC(row, (m) * 2))       = (half_t)(e0 * is);
            *(half_t*)(wP + swzC(row, (16 + m) * 2))  = (half_t)(e1 * is);
            *(half_t*)(wP + swzC(row, (32 + m) * 2))  = (half_t)(e2 * is);
            *(half_t*)(wP + swzC(row, (48 + m) * 2))  = (half_t)(e3 * is);
        }
    }

    // PV: pa from arena (contiguous 16B), bv from global vT (contiguous 16B)
    float4v oacc[2][4];
    #pragma unroll
    for (int tjd = 0; tjd < 2; ++tjd)
        #pragma unroll
        for (int ti = 0; ti < 4; ++ti) oacc[tjd][ti] = {0.f, 0.f, 0.f, 0.f};
    const half_t* vb_ = vt_ws + (size_t)(win * 8 + h) * 2048 + g * 8;
    #pragma unroll
    for (int kc = 0; kc < 2; ++kc) {
        half8 pa[4];
        #pragma unroll
        for (int ti = 0; ti < 4; ++ti)
            pa[ti] = *(const half8*)(wP + swzC(ti * 16 + m, kc * 64 + g * 16));
        #pragma unroll
        for (int tjd = 0; tjd < 2; ++tjd) {
            half8 bv = *(const half8*)(vb_ + (tjd * 16 + m) * 64 + kc * 32);
            #pragma unroll
            for (int ti = 0; ti < 4; ++ti)
                oacc[tjd][ti] = mfma16(pa[ti], bv, oacc[tjd][ti]);
        }
    }

    half_t* ag = attn_ws + (size_t)win * 16384;
    #pragma unroll
    for (int tjd = 0; tjd < 2; ++tjd)
        #pragma unroll
        for (int ti = 0; ti < 4; ++ti)
            #pragma unroll
            for (int r = 0; r < 4; ++r)
                ag[(size_t)(ti * 16 + g * 4 + r) * 256 + h * 32 + tjd * 16 + m] =
                    (half_t)oacc[tjd][ti][r];
}

// ---------------------------------------------------------------------------
// K3: proj GEMM (R10's lean kernel). (256,4), 16 waves/CU.
// ---------------------------------------------------------------------------
__global__ __launch_bounds__(256, 4) void proj_kernel(
    const half_t* __restrict__ attn_ws,
    const half_t* __restrict__ wprojT,
    const float* __restrict__ proj_b,
    float* __restrict__ out)
{
    __shared__ __align__(16) char smem[32768];
    char* xs = smem;

    const int win = blockIdx.x;
    const int tid = threadIdx.x;
    const int w = tid >> 6, lane = tid & 63, m = lane & 15, g = lane >> 4;

    const half_t* ag = attn_ws + (size_t)win * 16384;
    #pragma unroll
    for (int i = 0; i < 8; ++i) {
        int u = tid + i * 256;
        int row = u >> 5, c8 = u & 31;
        half8 v = *(const half8*)(ag + u * 8);
        *(half8*)(xs + swzA(row, c8 * 16)) = v;
    }
    __syncthreads();

    float* og = out + (size_t)win * 16384;
    #pragma unroll
    for (int cp = 0; cp < 2; ++cp) {
        const int oc0 = w * 64 + cp * 32;
        float4v pacc[2][4];
        #pragma unroll
        for (int c2 = 0; c2 < 2; ++c2)
            #pragma unroll
            for (int ti = 0; ti < 4; ++ti) pacc[c2][ti] = {0.f, 0.f, 0.f, 0.f};
        const half_t* wpb = wprojT + (size_t)(oc0 + m) * 256 + g * 8;
        #pragma unroll
        for (int kk = 0; kk < 8; ++kk) {
            half8 wf0 = *(const half8*)(wpb + kk * 32);
            half8 wf1 = *(const half8*)(wpb + 16 * 256 + kk * 32);
            #pragma unroll
            for (int ti = 0; ti < 4; ++ti) {
                half8 af = *(const half8*)(xs + swzA(ti * 16 + m, kk * 64 + g * 16));
                pacc[0][ti] = mfma16(af, wf0, pacc[0][ti]);
                pacc[1][ti] = mfma16(af, wf1, pacc[1][ti]);
            }
        }
        float pb0 = proj_b[oc0 + m], pb1 = proj_b[oc0 + 16 + m];
        #pragma unroll
        for (int c2 = 0; c2 < 2; ++c2)
            #pragma unroll
            for (int ti = 0; ti < 4; ++ti)
                #pragma unroll
                for (int r = 0; r < 4; ++r)
                    og[(ti * 16 + g * 4 + r) * 256 + oc0 + c2 * 16 + m] =
                        pacc[c2][ti][r] + (c2 ? pb1 : pb0);
    }
}

// ---------------------------------------------------------------------------
// Fallback (ws too small): R8's proven single fused kernel (237us).
// ---------------------------------------------------------------------------
__global__ __launch_bounds__(512, 2) void fused_fallback(
    const float* __restrict__ x,
    const half_t* __restrict__ wqkvT,
    const float* __restrict__ qkv_b,
    const half_t* __restrict__ wprojT,
    const float* __restrict__ proj_b,
    const float* __restrict__ rbp,
    float* __restrict__ out)
{
    __shared__ __align__(16) char smem[65536];
    char* xs  = smem;
    char* atn = smem;
    char* arenas = smem + 32768;

    const int b   = blockIdx.x;
    const int tid = threadIdx.x;
    const int w    = tid >> 6;
    const int lane = tid & 63;
    const int m = lane & 15;
    const int g = lane >> 4;
    char* wA  = arenas + w * 4096;
    char* vts = xs + w * 4096;

    const float* xg = x + (size_t)b * 16384;
    #pragma unroll
    for (int i = 0; i < 8; ++i) {
        int u = tid + i * 512;
        int row = u >> 6, c4 = u & 63;
        float4v xv = *(const float4v*)(xg + u * 4);
        half4 hv;
        hv[0] = (half_t)xv[0]; hv[1] = (half_t)xv[1];
        hv[2] = (half_t)xv[2]; hv[3] = (half_t)xv[3];
        *(half4*)(xs + swzA(row, c4 * 8)) = hv;
    }
    __syncthreads();

    float4v qb[2][2];
    #pragma unroll
    for (int pt = 0; pt < 2; ++pt)
        #pragma unroll
        for (int c2 = 0; c2 < 2; ++c2)
            qb[pt][c2] = *(const float4v*)(qkv_b + pt * 256 + w * 32 + c2 * 16 + g * 4);

    half8 aq[4], bk[4];
    {
        float4v qa[2][4], ka[2][4];
        #pragma unroll
        for (int c2 = 0; c2 < 2; ++c2)
            #pragma unroll
            for (int ti = 0; ti < 4; ++ti) {
                qa[c2][ti] = {0.f, 0.f, 0.f, 0.f};
                ka[c2][ti] = {0.f, 0.f, 0.f, 0.f};
            }
        const half_t* wqb = wqkvT + (size_t)(w * 32 + m) * 256 + g * 8;
        #pragma unroll
        for (int kk = 0; kk < 8; ++kk) {
            half8 af[4];
            #pragma unroll
            for (int ti = 0; ti < 4; ++ti)
                af[ti] = *(const half8*)(xs + swzA(ti * 16 + m, kk * 64 + g * 16));
            half8 wq0 = *(const half8*)(wqb + kk * 32);
            half8 wq1 = *(const half8*)(wqb + 16 * 256 + kk * 32);
            half8 wk0 = *(const half8*)(wqb + 256 * 256 + kk * 32);
            half8 wk1 = *(const half8*)(wqb + 272 * 256 + kk * 32);
            #pragma unroll
            for (int ti = 0; ti < 4; ++ti) {
                qa[0][ti] = mfma16(wq0, af[ti], qa[0][ti]);
                qa[1][ti] = mfma16(wq1, af[ti], qa[1][ti]);
                ka[0][ti] = mfma16(wk0, af[ti], ka[0][ti]);
                ka[1][ti] = mfma16(wk1, af[ti], ka[1][ti]);
            }
        }
        #pragma unroll
        for (int c2 = 0; c2 < 2; ++c2)
            #pragma unroll
            for (int ti = 0; ti < 4; ++ti) {
                half4 t;
                #pragma unroll
                for (int r = 0; r < 4; ++r) t[r] = (half_t)(qa[c2][ti][r] + qb[0][c2][r]);
                *(half4*)(wA + ti * 1024 + swzB(m, (c2 * 16 + g * 4) * 2)) = t;
            }
        #pragma unroll
        for (int ti = 0; ti < 4; ++ti)
            aq[ti] = *(const half8*)(wA + ti * 1024 + swzB(m, g * 16));
        __builtin_amdgcn_sched_barrier(0);
        #pragma unroll
        for (int c2 = 0; c2 < 2; ++c2)
            #pragma unroll
            for (int ti = 0; ti < 4; ++ti) {
                half4 t;
                #pragma unroll
                for (int r = 0; r < 4; ++r) t[r] = (half_t)(ka[c2][ti][r] + qb[1][c2][r]);
                *(half4*)(wA + ti * 1024 + swzB(m, (c2 * 16 + g * 4) * 2)) = t;
            }
        #pragma unroll
        for (int ti = 0; ti < 4; ++ti)
            bk[ti] = *(const half8*)(wA + ti * 1024 + swzB(m, g * 16));
        __builtin_amdgcn_sched_barrier(0);
    }

    half4 ph[4][4];
    const float* rbh = rbp + w * 4096;
    #pragma unroll
    for (int ti = 0; ti < 4; ++ti) {
        float4v z = {0.f, 0.f, 0.f, 0.f};
        float4v s0 = mfma16(aq[ti], bk[0], z);
        float4v s1 = mfma16(aq[ti], bk[1], z);
        float4v s2 = mfma16(aq[ti], bk[2], z);
        float4v s3 = mfma16(aq[ti], bk[3], z);
        #pragma unroll
        for (int r = 0; r < 4; ++r) {
            float4v rb = *(const float4v*)(rbh + (ti * 16 + g * 4 + r) * 64 + m * 4);
            float e0 = __expf(s0[r] * QK_SCALE + rb[0]);
            float e1 = __expf(s1[r] * QK_SCALE + rb[1]);
            float e2 = __expf(s2[r] * QK_SCALE + rb[2]);
            float e3 = __expf(s3[r] * QK_SCALE + rb[3]);
            float s = e0 + e1 + e2 + e3;
            s += __shfl_xor(s, 1); s += __shfl_xor(s, 2);
            s += __shfl_xor(s, 4); s += __shfl_xor(s, 8);
            float is = 1.0f / s;
            ph[ti][0][r] = (half_t)(e0 * is);
            ph[ti][1][r] = (half_t)(e1 * is);
            ph[ti][2][r] = (half_t)(e2 * is);
            ph[ti][3][r] = (half_t)(e3 * is);
        }
    }

    half4 vh[2][4];
    {
        float4v va[2][4];
        #pragma unroll
        for (int c2 = 0; c2 < 2; ++c2)
            #pragma unroll
            for (int ti = 0; ti < 4; ++ti) va[c2][ti] = {0.f, 0.f, 0.f, 0.f};
        const half_t* wvb = wqkvT + (size_t)(512 + w * 32 + m) * 256 + g * 8;
        #pragma unroll
        for (int kk = 0; kk < 8; ++kk) {
            half8 wv0 = *(const half8*)(wvb + kk * 32);
            half8 wv1 = *(const half8*)(wvb + 16 * 256 + kk * 32);
            #pragma unroll
            for (int ti = 0; ti < 4; ++ti) {
                half8 af = *(const half8*)(xs + swzA(ti * 16 + m, kk * 64 + g * 16));
                va[0][ti] = mfma16(af, wv0, va[0][ti]);
                va[1][ti] = mfma16(af, wv1, va[1][ti]);
            }
        }
        float vb0 = qkv_b[512 + w * 32 + m], vb1 = qkv_b[512 + w * 32 + 16 + m];
        #pragma unroll
        for (int c2 = 0; c2 < 2; ++c2)
            #pragma unroll
            for (int ti = 0; ti < 4; ++ti)
                #pragma unroll
                for (int r = 0; r < 4; ++r)
                    vh[c2][ti][r] = (half_t)(va[c2][ti][r] + (c2 ? vb1 : vb0));
    }
    __syncthreads();

    #pragma unroll
    for (int c2 = 0; c2 < 2; ++c2)
        #pragma unroll
        for (int ti = 0; ti < 4; ++ti)
            *(half4*)(vts + swzC(c2 * 16 + m, ti * 32 + g * 8)) = vh[c2][ti];

    float4v oacc[2][4];
    #pragma unroll
    for (int tjd = 0; tjd < 2; ++tjd)
        #pragma unroll
        for (int ti = 0; ti < 4; ++ti) oacc[tjd][ti] = {0.f, 0.f, 0.f, 0.f};
    #pragma unroll
    for (int nc = 0; nc < 2; ++nc) {
        #pragma unroll
        for (int ti = 0; ti < 4; ++ti)
            #pragma unroll
            for (int t2 = 0; t2 < 2; ++t2)
                #pragma unroll
                for (int r = 0; r < 4; ++r)
                    *(half_t*)(wA + swzB(ti * 16 + g * 4 + r, (t2 * 16 + m) * 2)) =
                        ph[ti][nc * 2 + t2][r];
        half8 pa[4];
        #pragma unroll
        for (int ti = 0; ti < 4; ++ti)
            pa[ti] = *(const half8*)(wA + swzB(ti * 16 + m, g * 16));
        #pragma unroll
        for (int tjd = 0; tjd < 2; ++tjd) {
            half8 bv = *(const half8*)(vts + swzC(tjd * 16 + m, nc * 64 + g * 16));
            #pragma unroll
            for (int ti = 0; ti < 4; ++ti)
                oacc[tjd][ti] = mfma16(pa[ti], bv, oacc[tjd][ti]);
        }
        __builtin_amdgcn_sched_barrier(0);
    }
    __syncthreads();

    #pragma unroll
    for (int tjd = 0; tjd < 2; ++tjd)
        #pragma unroll
        for (int ti = 0; ti < 4; ++ti)
            #pragma unroll
            for (int r = 0; r < 4; ++r)
                *(half_t*)(atn + swzA(ti * 16 + g * 4 + r, (w * 32 + tjd * 16 + m) * 2)) =
                    (half_t)oacc[tjd][ti][r];
    __syncthreads();

    float* og = out + (size_t)b * 16384;
    const int oc0 = w * 32;
    float4v pacc[2][4];
    #pragma unroll
    for (int c2 = 0; c2 < 2; ++c2)
        #pragma unroll
        for (int ti = 0; ti < 4; ++ti) pacc[c2][ti] = {0.f, 0.f, 0.f, 0.f};
    const half_t* wpb = wprojT + (size_t)(oc0 + m) * 256 + g * 8;
    #pragma unroll
    for (int kk = 0; kk < 8; ++kk) {
        half8 wf0 = *(const half8*)(wpb + kk * 32);
        half8 wf1 = *(const half8*)(wpb + 16 * 256 + kk * 32);
        #pragma unroll
        for (int ti = 0; ti < 4; ++ti) {
            half8 af = *(const half8*)(atn + swzA(ti * 16 + m, kk * 64 + g * 16));
            pacc[0][ti] = mfma16(af, wf0, pacc[0][ti]);
            pacc[1][ti] = mfma16(af, wf1, pacc[1][ti]);
        }
    }
    float pb0 = proj_b[oc0 + m], pb1 = proj_b[oc0 + 16 + m];
    #pragma unroll
    for (int c2 = 0; c2 < 2; ++c2)
        #pragma unroll
        for (int ti = 0; ti < 4; ++ti)
            #pragma unroll
            for (int r = 0; r < 4; ++r)
                og[(ti * 16 + g * 4 + r) * 256 + oc0 + c2 * 16 + m] =
                    pacc[c2][ti][r] + (c2 ? pb1 : pb0);
}

extern "C" void kernel_launch(void* const* d_in, const int* in_sizes, int n_in,
                              void* d_out, int out_size, void* d_ws, size_t ws_size,
                              hipStream_t stream) {
    const float* x          = (const float*)d_in[0];
    const float* qkv_w      = (const float*)d_in[1];
    const float* qkv_b      = (const float*)d_in[2];
    const float* proj_w     = (const float*)d_in[3];
    const float* proj_b     = (const float*)d_in[4];
    const float* pos_proj_w = (const float*)d_in[5];
    const float* pos_proj_b = (const float*)d_in[6];
    const float* ln1_g = (const float*)d_in[7];
    const float* ln1_b = (const float*)d_in[8];
    const float* fc1_w = (const float*)d_in[9];
    const float* fc1_b = (const float*)d_in[10];
    const float* ln2_g = (const float*)d_in[11];
    const float* ln2_b = (const float*)d_in[12];
    const float* fc2_w = (const float*)d_in[13];
    const float* fc2_b = (const float*)d_in[14];
    const float* ln3_g = (const float*)d_in[15];
    const float* ln3_b = (const float*)d_in[16];
    const float* fc3_w = (const float*)d_in[17];
    const float* fc3_b = (const float*)d_in[18];
    const float* biases = (const float*)d_in[19];
    const int*  rel_idx = (const int*)d_in[20];

    half_t* wqkvT  = (half_t*)d_ws;
    half_t* wprojT = (half_t*)((char*)d_ws + 393216);
    float*  rbp    = (float*)((char*)d_ws + 524288);

    const int B = in_sizes[0] / (64 * 256);
    // intermediates: q,k (fp16 row-major) live in d_out (exact fit, dead by
    // proj); vT + attn live in ws.
    half_t* q_ws    = (half_t*)d_out;
    half_t* k_ws    = q_ws + (size_t)B * 16384;
    half_t* vt_ws   = (half_t*)((char*)d_ws + 655360);
    half_t* attn_ws = vt_ws + (size_t)B * 16384;
    const size_t need = 655360 + (size_t)B * 65536;

    prep_kernel<<<65, 256, 0, stream>>>(qkv_w, proj_w, biases, pos_proj_w, pos_proj_b,
                                        ln1_g, ln1_b, fc1_w, fc1_b,
                                        ln2_g, ln2_b, fc2_w, fc2_b,
                                        ln3_g, ln3_b, fc3_w, fc3_b,
                                        rel_idx, wqkvT, wprojT, rbp);
    if (ws_size >= need) {
        qkv_gemm_kernel<<<B, 256, 0, stream>>>(x, wqkvT, qkv_b, q_ws, k_ws, vt_ws);
        attn_kernel<<<B * 2, 256, 0, stream>>>(q_ws, k_ws, vt_ws, rbp, attn_ws);
        proj_kernel<<<B, 256, 0, stream>>>(attn_ws, wprojT, proj_b, (float*)d_out);
    } else {
        fused_fallback<<<B, 512, 0, stream>>>(x, wqkvT, qkv_b, wprojT, proj_b, rbp,
                                              (float*)d_out);
    }
}

// Round 13
// 308.018 us; speedup vs baseline: 1.2802x; 1.2802x over previous
//
#include <hip/hip_runtime.h>

typedef _Float16 half_t;
typedef __attribute__((ext_vector_type(8))) _Float16 half8;
typedef __attribute__((ext_vector_type(4))) _Float16 half4;
typedef __attribute__((ext_vector_type(4))) float float4v;

#define LN_EPS 1e-5f
#define QK_SCALE 0.17677669529663687f   // 32^-0.5

static __device__ __forceinline__ float4v mfma16(half8 a, half8 b, float4v c) {
    return __builtin_amdgcn_mfma_f32_16x16x32_f16(a, b, c, 0, 0, 0);
}

// 512B rows, XOR key (row>>1)&7  (x tile in LDS)
static __device__ __forceinline__ int swzA(int row, int colByte) {
    return row * 512 + ((((colByte >> 4) ^ ((row >> 1) & 7)) << 4) | (colByte & 15));
}
// 64B rows, XOR key (row>>1)&3  (fallback kernel arenas)
static __device__ __forceinline__ int swzB(int row, int colByte) {
    return row * 64 + ((((colByte >> 4) ^ ((row >> 1) & 3)) << 4) | (colByte & 15));
}
// 128B rows, XOR key row&7  (fallback kernel vT slots)
static __device__ __forceinline__ int swzC(int row, int colByte) {
    return row * 128 + ((((colByte >> 4) ^ (row & 7)) << 4) | (colByte & 15));
}

static __device__ void ln_relu16(float* h, const float* __restrict__ g, const float* __restrict__ b) {
    float m = 0.f;
    for (int j = 0; j < 16; ++j) m += h[j];
    m *= (1.0f / 16.0f);
    float v = 0.f;
    for (int j = 0; j < 16; ++j) { float d = h[j] - m; v += d * d; }
    v *= (1.0f / 16.0f);
    float rs = rsqrtf(v + LN_EPS);
    for (int j = 0; j < 16; ++j) {
        float t = (h[j] - m) * rs * g[j] + b[j];
        h[j] = t > 0.f ? t : 0.f;
    }
}

// ---------------------------------------------------------------------------
// prep: weight transpose+fp16, pos-bias MLP, rel-bias table rbp[h][row][m][tj]
// ---------------------------------------------------------------------------
__global__ void prep_kernel(
    const float* __restrict__ qkv_w,   // [256,768]
    const float* __restrict__ proj_w,  // [256,256]
    const float* __restrict__ biases,  // [225,2]
    const float* __restrict__ pos_w, const float* __restrict__ pos_b,
    const float* __restrict__ ln1_g, const float* __restrict__ ln1_b,
    const float* __restrict__ fc1_w, const float* __restrict__ fc1_b,
    const float* __restrict__ ln2_g, const float* __restrict__ ln2_b,
    const float* __restrict__ fc2_w, const float* __restrict__ fc2_b,
    const float* __restrict__ ln3_g, const float* __restrict__ ln3_b,
    const float* __restrict__ fc3_w, const float* __restrict__ fc3_b,
    const int* __restrict__ rel_idx,   // [64,64]
    half_t* __restrict__ wqkvT,        // [768,256]
    half_t* __restrict__ wprojT,       // [256,256]
    float* __restrict__ rbp)           // [8][64][16][4]
{
    __shared__ float tile[64][65];
    __shared__ float pos_s[225][8];
    const int t = blockIdx.x;
    const int tid = threadIdx.x;

    if (t < 64) {
        const float* src; half_t* dst; int ncols, rg, cg;
        if (t < 48) { src = qkv_w;  dst = wqkvT;  ncols = 768; rg = t / 12;      cg = t % 12; }
        else        { src = proj_w; dst = wprojT; ncols = 256; rg = (t-48) >> 2; cg = (t-48) & 3; }
        const int r0 = tid >> 6, c = tid & 63;
        for (int i = 0; i < 16; ++i) {
            int r = i * 4 + r0;
            tile[r][c] = src[(rg * 64 + r) * ncols + cg * 64 + c];
        }
        __syncthreads();
        for (int i = 0; i < 16; ++i) {
            int r = i * 4 + r0;
            dst[(cg * 64 + r) * 256 + rg * 64 + c] = (half_t)tile[c][r];
        }
    } else {
        if (tid < 225) {
            float h[16], h2[16];
            float b0 = biases[tid * 2], b1 = biases[tid * 2 + 1];
            for (int j = 0; j < 16; ++j) h[j] = b0 * pos_w[j] + b1 * pos_w[16 + j] + pos_b[j];
            ln_relu16(h, ln1_g, ln1_b);
            for (int j = 0; j < 16; ++j) {
                float s = fc1_b[j];
                for (int k = 0; k < 16; ++k) s += h[k] * fc1_w[k * 16 + j];
                h2[j] = s;
            }
            ln_relu16(h2, ln2_g, ln2_b);
            for (int j = 0; j < 16; ++j) {
                float s = fc2_b[j];
                for (int k = 0; k < 16; ++k) s += h2[k] * fc2_w[k * 16 + j];
                h[j] = s;
            }
            ln_relu16(h, ln3_g, ln3_b);
            for (int j = 0; j < 8; ++j) {
                float s = fc3_b[j];
                for (int k = 0; k < 16; ++k) s += h[k] * fc3_w[k * 8 + j];
                pos_s[tid][j] = s;
            }
        }
        __syncthreads();
        for (int e = tid; e < 8 * 64 * 64; e += 256) {
            int hh = e >> 12, rem = e & 4095;
            int row = rem >> 6, c = rem & 63;
            int tj = c >> 4, mm = c & 15;
            rbp[hh * 4096 + row * 64 + mm * 4 + tj] = pos_s[rel_idx[row * 64 + c]][hh];
        }
    }
}

// ---------------------------------------------------------------------------
// K1: QKV GEMM per window. MFMA C-layout direct stores were 2B scalars into
// 32B segments (2x HBM write amplification, R11). Fix: wave-private LDS
// staging (padded strides 80/144), then half8 stores covering full aligned
// lines. LDS 32K xs + 4x2560 staging = 42KB, (256,3), 3 blocks/CU.
// ---------------------------------------------------------------------------
__global__ __launch_bounds__(256, 3) void qkv_gemm_kernel(
    const float* __restrict__ x,
    const half_t* __restrict__ wqkvT,
    const float* __restrict__ qkv_b,
    half_t* __restrict__ q_ws,
    half_t* __restrict__ k_ws,
    half_t* __restrict__ vt_ws)
{
    __shared__ __align__(16) char smem[43008];
    char* xs = smem;
    const int win = blockIdx.x;
    const int tid = threadIdx.x;
    const int w = tid >> 6, lane = tid & 63, m = lane & 15, g = lane >> 4;
    char* stg = smem + 32768 + w * 2560;

    const float* xg = x + (size_t)win * 16384;
    #pragma unroll
    for (int i = 0; i < 16; ++i) {
        int u = tid + i * 256;
        int row = u >> 6, c4 = u & 63;
        float4v xv = *(const float4v*)(xg + u * 4);
        half4 hv;
        hv[0] = (half_t)xv[0]; hv[1] = (half_t)xv[1];
        hv[2] = (half_t)xv[2]; hv[3] = (half_t)xv[3];
        *(half4*)(xs + swzA(row, c4 * 8)) = hv;
    }
    __syncthreads();

    #pragma unroll
    for (int p = 0; p < 6; ++p) {
        const int ct0 = w * 12 + p * 2;
        float4v acc[2][4];
        #pragma unroll
        for (int c2 = 0; c2 < 2; ++c2)
            #pragma unroll
            for (int ti = 0; ti < 4; ++ti) acc[c2][ti] = {0.f, 0.f, 0.f, 0.f};
        const half_t* wb = wqkvT + (size_t)(ct0 * 16 + m) * 256 + g * 8;
        #pragma unroll
        for (int kk = 0; kk < 8; ++kk) {
            half8 af[4];
            #pragma unroll
            for (int ti = 0; ti < 4; ++ti)
                af[ti] = *(const half8*)(xs + swzA(ti * 16 + m, kk * 64 + g * 16));
            half8 wf0 = *(const half8*)(wb + kk * 32);
            half8 wf1 = *(const half8*)(wb + 16 * 256 + kk * 32);
            #pragma unroll
            for (int ti = 0; ti < 4; ++ti) {
                acc[0][ti] = mfma16(af[ti], wf0, acc[0][ti]);   // A=x rows n, B=W cols
                acc[1][ti] = mfma16(af[ti], wf1, acc[1][ti]);
            }
        }
        if (ct0 < 32) {
            // q/k: stage [32 n][32 cols] (stride 80) per half, store 64B rows
            const float b0 = qkv_b[ct0 * 16 + m];
            const float b1 = qkv_b[ct0 * 16 + 16 + m];
            half_t* dst = (ct0 < 16 ? q_ws : k_ws) + (size_t)win * 16384 + ((ct0 & 15) * 16);
            #pragma unroll
            for (int hf = 0; hf < 2; ++hf) {
                #pragma unroll
                for (int c2 = 0; c2 < 2; ++c2)
                    #pragma unroll
                    for (int t2 = 0; t2 < 2; ++t2)
                        #pragma unroll
                        for (int r = 0; r < 4; ++r)
                            *(half_t*)(stg + (t2 * 16 + g * 4 + r) * 80 + (c2 * 16 + m) * 2) =
                                (half_t)(acc[c2][hf * 2 + t2][r] + (c2 ? b1 : b0));
                __builtin_amdgcn_sched_barrier(0);
                #pragma unroll
                for (int i = 0; i < 2; ++i) {
                    const int rl = i * 16 + (lane >> 2);
                    half8 vv = *(const half8*)(stg + rl * 80 + (lane & 3) * 16);
                    *(half8*)(dst + (size_t)(hf * 32 + rl) * 256 + (lane & 3) * 8) = vv;
                }
                __builtin_amdgcn_sched_barrier(0);
            }
        } else {
            // v: per d-tile stage [16 d][64 n] (stride 144), store 128B rows
            const int vb0 = ct0 - 32;
            #pragma unroll
            for (int c2 = 0; c2 < 2; ++c2) {
                const int vbi = vb0 + c2;
                const float bias = qkv_b[(ct0 + c2) * 16 + m];
                #pragma unroll
                for (int ti = 0; ti < 4; ++ti) {
                    half4 pk;
                    #pragma unroll
                    for (int r = 0; r < 4; ++r) pk[r] = (half_t)(acc[c2][ti][r] + bias);
                    *(half4*)(stg + m * 144 + (ti * 16 + g * 4) * 2) = pk;
                }
                __builtin_amdgcn_sched_barrier(0);
                half_t* vd = vt_ws + ((size_t)(win * 8 + (vbi >> 1)) * 32 + (vbi & 1) * 16) * 64;
                #pragma unroll
                for (int i = 0; i < 2; ++i) {
                    const int rl = i * 8 + (lane >> 3);
                    half8 vv = *(const half8*)(stg + rl * 144 + (lane & 7) * 16);
                    *(half8*)(vd + (size_t)rl * 64 + (lane & 7) * 8) = vv;
                }
                __builtin_amdgcn_sched_barrier(0);
            }
        }
    }
}

// ---------------------------------------------------------------------------
// K2: attention. 4 waves = 4 heads; zero __syncthreads. q/k row-major and vT
// give contiguous 16B fragment loads. P arena: R12 BUG was stride 80 for a
// 64-col (128B) P row -> rows overlapped + OOB. Fixed: stride 144 (128B
// payload + 16B pad; 144/4 = 36 = 4 mod 32 -> b128 reads 2-way = free),
// arena 9216B/wave, smem 36864.
// ---------------------------------------------------------------------------
__global__ __launch_bounds__(256, 3) void attn_kernel(
    const half_t* __restrict__ q_ws,
    const half_t* __restrict__ k_ws,
    const half_t* __restrict__ vt_ws,
    const float* __restrict__ rbp,
    half_t* __restrict__ attn_ws)
{
    __shared__ __align__(16) char smem[36864];
    const int bb = blockIdx.x, win = bb >> 1;
    const int tid = threadIdx.x;
    const int w = tid >> 6, lane = tid & 63, m = lane & 15, g = lane >> 4;
    const int h = (bb & 1) * 4 + w;
    char* wP = smem + w * 9216;        // [64 rows][144B stride, 128B payload]

    const half_t* qb_ = q_ws + (size_t)win * 16384 + h * 32 + g * 8;
    const half_t* kb_ = k_ws + (size_t)win * 16384 + h * 32 + g * 8;
    half8 aq[4], bk[4];
    #pragma unroll
    for (int t = 0; t < 4; ++t) {
        aq[t] = *(const half8*)(qb_ + (size_t)(t * 16 + m) * 256);
        bk[t] = *(const half8*)(kb_ + (size_t)(t * 16 + m) * 256);
    }

    const float* rbh = rbp + h * 4096;
    #pragma unroll
    for (int ti = 0; ti < 4; ++ti) {
        float4v z = {0.f, 0.f, 0.f, 0.f};
        float4v s0 = mfma16(aq[ti], bk[0], z);
        float4v s1 = mfma16(aq[ti], bk[1], z);
        float4v s2 = mfma16(aq[ti], bk[2], z);
        float4v s3 = mfma16(aq[ti], bk[3], z);
        #pragma unroll
        for (int r = 0; r < 4; ++r) {
            const int row = ti * 16 + g * 4 + r;
            float4v rb = *(const float4v*)(rbh + row * 64 + m * 4);
            float e0 = __expf(s0[r] * QK_SCALE + rb[0]);
            float e1 = __expf(s1[r] * QK_SCALE + rb[1]);
            float e2 = __expf(s2[r] * QK_SCALE + rb[2]);
            float e3 = __expf(s3[r] * QK_SCALE + rb[3]);
            float s = e0 + e1 + e2 + e3;
            s += __shfl_xor(s, 1); s += __shfl_xor(s, 2);
            s += __shfl_xor(s, 4); s += __shfl_xor(s, 8);
            float is = 1.0f / s;
            *(half_t*)(wP + row * 144 + m * 2)        = (half_t)(e0 * is);
            *(half_t*)(wP + row * 144 + (16 + m) * 2) = (half_t)(e1 * is);
            *(half_t*)(wP + row * 144 + (32 + m) * 2) = (half_t)(e2 * is);
            *(half_t*)(wP + row * 144 + (48 + m) * 2) = (half_t)(e3 * is);
        }
    }

    float4v oacc[2][4];
    #pragma unroll
    for (int tjd = 0; tjd < 2; ++tjd)
        #pragma unroll
        for (int ti = 0; ti < 4; ++ti) oacc[tjd][ti] = {0.f, 0.f, 0.f, 0.f};
    const half_t* vb_ = vt_ws + (size_t)(win * 8 + h) * 2048 + g * 8;
    #pragma unroll
    for (int kc = 0; kc < 2; ++kc) {
        half8 pa[4];
        #pragma unroll
        for (int ti = 0; ti < 4; ++ti)
            pa[ti] = *(const half8*)(wP + (ti * 16 + m) * 144 + kc * 64 + g * 16);
        #pragma unroll
        for (int tjd = 0; tjd < 2; ++tjd) {
            half8 bv = *(const half8*)(vb_ + (tjd * 16 + m) * 64 + kc * 32);
            #pragma unroll
            for (int ti = 0; ti < 4; ++ti)
                oacc[tjd][ti] = mfma16(pa[ti], bv, oacc[tjd][ti]);
        }
    }
    __builtin_amdgcn_sched_barrier(0);   // pa reads before attn-out overwrite

    // stage attn [64 n][32 cols] (stride 144), then 4 stores of 16rows x 64B
    #pragma unroll
    for (int tjd = 0; tjd < 2; ++tjd)
        #pragma unroll
        for (int ti = 0; ti < 4; ++ti)
            #pragma unroll
            for (int r = 0; r < 4; ++r)
                *(half_t*)(wP + (ti * 16 + g * 4 + r) * 144 + (tjd * 16 + m) * 2) =
                    (half_t)oacc[tjd][ti][r];
    __builtin_amdgcn_sched_barrier(0);
    half_t* ag = attn_ws + (size_t)win * 16384 + h * 32;
    #pragma unroll
    for (int i = 0; i < 4; ++i) {
        const int rl = i * 16 + (lane >> 2);
        half8 vv = *(const half8*)(wP + rl * 144 + (lane & 3) * 16);
        *(half8*)(ag + (size_t)rl * 256 + (lane & 3) * 8) = vv;
    }
}

// ---------------------------------------------------------------------------
// K3: proj GEMM. (256,4), 16 waves/CU. fp32 out stores already 64B-coalesced.
// ---------------------------------------------------------------------------
__global__ __launch_bounds__(256, 4) void proj_kernel(
    const half_t* __restrict__ attn_ws,
    const half_t* __restrict__ wprojT,
    const float* __restrict__ proj_b,
    float* __restrict__ out)
{
    __shared__ __align__(16) char smem[32768];
    char* xs = smem;

    const int win = blockIdx.x;
    const int tid = threadIdx.x;
    const int w = tid >> 6, lane = tid & 63, m = lane & 15, g = lane >> 4;

    const half_t* ag = attn_ws + (size_t)win * 16384;
    #pragma unroll
    for (int i = 0; i < 8; ++i) {
        int u = tid + i * 256;
        int row = u >> 5, c8 = u & 31;
        half8 v = *(const half8*)(ag + u * 8);
        *(half8*)(xs + swzA(row, c8 * 16)) = v;
    }
    __syncthreads();

    float* og = out + (size_t)win * 16384;
    #pragma unroll
    for (int cp = 0; cp < 2; ++cp) {
        const int oc0 = w * 64 + cp * 32;
        float4v pacc[2][4];
        #pragma unroll
        for (int c2 = 0; c2 < 2; ++c2)
            #pragma unroll
            for (int ti = 0; ti < 4; ++ti) pacc[c2][ti] = {0.f, 0.f, 0.f, 0.f};
        const half_t* wpb = wprojT + (size_t)(oc0 + m) * 256 + g * 8;
        #pragma unroll
        for (int kk = 0; kk < 8; ++kk) {
            half8 wf0 = *(const half8*)(wpb + kk * 32);
            half8 wf1 = *(const half8*)(wpb + 16 * 256 + kk * 32);
            #pragma unroll
            for (int ti = 0; ti < 4; ++ti) {
                half8 af = *(const half8*)(xs + swzA(ti * 16 + m, kk * 64 + g * 16));
                pacc[0][ti] = mfma16(af, wf0, pacc[0][ti]);
                pacc[1][ti] = mfma16(af, wf1, pacc[1][ti]);
            }
        }
        float pb0 = proj_b[oc0 + m], pb1 = proj_b[oc0 + 16 + m];
        #pragma unroll
        for (int c2 = 0; c2 < 2; ++c2)
            #pragma unroll
            for (int ti = 0; ti < 4; ++ti)
                #pragma unroll
                for (int r = 0; r < 4; ++r)
                    og[(ti * 16 + g * 4 + r) * 256 + oc0 + c2 * 16 + m] =
                        pacc[c2][ti][r] + (c2 ? pb1 : pb0);
    }
}

// ---------------------------------------------------------------------------
// Fallback (ws too small): R8's proven single fused kernel (237us).
// ---------------------------------------------------------------------------
__global__ __launch_bounds__(512, 2) void fused_fallback(
    const float* __restrict__ x,
    const half_t* __restrict__ wqkvT,
    const float* __restrict__ qkv_b,
    const half_t* __restrict__ wprojT,
    const float* __restrict__ proj_b,
    const float* __restrict__ rbp,
    float* __restrict__ out)
{
    __shared__ __align__(16) char smem[65536];
    char* xs  = smem;
    char* atn = smem;
    char* arenas = smem + 32768;

    const int b   = blockIdx.x;
    const int tid = threadIdx.x;
    const int w    = tid >> 6;
    const int lane = tid & 63;
    const int m = lane & 15;
    const int g = lane >> 4;
    char* wA  = arenas + w * 4096;
    char* vts = xs + w * 4096;

    const float* xg = x + (size_t)b * 16384;
    #pragma unroll
    for (int i = 0; i < 8; ++i) {
        int u = tid + i * 512;
        int row = u >> 6, c4 = u & 63;
        float4v xv = *(const float4v*)(xg + u * 4);
        half4 hv;
        hv[0] = (half_t)xv[0]; hv[1] = (half_t)xv[1];
        hv[2] = (half_t)xv[2]; hv[3] = (half_t)xv[3];
        *(half4*)(xs + swzA(row, c4 * 8)) = hv;
    }
    __syncthreads();

    float4v qb[2][2];
    #pragma unroll
    for (int pt = 0; pt < 2; ++pt)
        #pragma unroll
        for (int c2 = 0; c2 < 2; ++c2)
            qb[pt][c2] = *(const float4v*)(qkv_b + pt * 256 + w * 32 + c2 * 16 + g * 4);

    half8 aq[4], bk[4];
    {
        float4v qa[2][4], ka[2][4];
        #pragma unroll
        for (int c2 = 0; c2 < 2; ++c2)
            #pragma unroll
            for (int ti = 0; ti < 4; ++ti) {
                qa[c2][ti] = {0.f, 0.f, 0.f, 0.f};
                ka[c2][ti] = {0.f, 0.f, 0.f, 0.f};
            }
        const half_t* wqb = wqkvT + (size_t)(w * 32 + m) * 256 + g * 8;
        #pragma unroll
        for (int kk = 0; kk < 8; ++kk) {
            half8 af[4];
            #pragma unroll
            for (int ti = 0; ti < 4; ++ti)
                af[ti] = *(const half8*)(xs + swzA(ti * 16 + m, kk * 64 + g * 16));
            half8 wq0 = *(const half8*)(wqb + kk * 32);
            half8 wq1 = *(const half8*)(wqb + 16 * 256 + kk * 32);
            half8 wk0 = *(const half8*)(wqb + 256 * 256 + kk * 32);
            half8 wk1 = *(const half8*)(wqb + 272 * 256 + kk * 32);
            #pragma unroll
            for (int ti = 0; ti < 4; ++ti) {
                qa[0][ti] = mfma16(wq0, af[ti], qa[0][ti]);
                qa[1][ti] = mfma16(wq1, af[ti], qa[1][ti]);
                ka[0][ti] = mfma16(wk0, af[ti], ka[0][ti]);
                ka[1][ti] = mfma16(wk1, af[ti], ka[1][ti]);
            }
        }
        #pragma unroll
        for (int c2 = 0; c2 < 2; ++c2)
            #pragma unroll
            for (int ti = 0; ti < 4; ++ti) {
                half4 t;
                #pragma unroll
                for (int r = 0; r < 4; ++r) t[r] = (half_t)(qa[c2][ti][r] + qb[0][c2][r]);
                *(half4*)(wA + ti * 1024 + swzB(m, (c2 * 16 + g * 4) * 2)) = t;
            }
        #pragma unroll
        for (int ti = 0; ti < 4; ++ti)
            aq[ti] = *(const half8*)(wA + ti * 1024 + swzB(m, g * 16));
        __builtin_amdgcn_sched_barrier(0);
        #pragma unroll
        for (int c2 = 0; c2 < 2; ++c2)
            #pragma unroll
            for (int ti = 0; ti < 4; ++ti) {
                half4 t;
                #pragma unroll
                for (int r = 0; r < 4; ++r) t[r] = (half_t)(ka[c2][ti][r] + qb[1][c2][r]);
                *(half4*)(wA + ti * 1024 + swzB(m, (c2 * 16 + g * 4) * 2)) = t;
            }
        #pragma unroll
        for (int ti = 0; ti < 4; ++ti)
            bk[ti] = *(const half8*)(wA + ti * 1024 + swzB(m, g * 16));
        __builtin_amdgcn_sched_barrier(0);
    }

    half4 ph[4][4];
    const float* rbh = rbp + w * 4096;
    #pragma unroll
    for (int ti = 0; ti < 4; ++ti) {
        float4v z = {0.f, 0.f, 0.f, 0.f};
        float4v s0 = mfma16(aq[ti], bk[0], z);
        float4v s1 = mfma16(aq[ti], bk[1], z);
        float4v s2 = mfma16(aq[ti], bk[2], z);
        float4v s3 = mfma16(aq[ti], bk[3], z);
        #pragma unroll
        for (int r = 0; r < 4; ++r) {
            float4v rb = *(const float4v*)(rbh + (ti * 16 + g * 4 + r) * 64 + m * 4);
            float e0 = __expf(s0[r] * QK_SCALE + rb[0]);
            float e1 = __expf(s1[r] * QK_SCALE + rb[1]);
            float e2 = __expf(s2[r] * QK_SCALE + rb[2]);
            float e3 = __expf(s3[r] * QK_SCALE + rb[3]);
            float s = e0 + e1 + e2 + e3;
            s += __shfl_xor(s, 1); s += __shfl_xor(s, 2);
            s += __shfl_xor(s, 4); s += __shfl_xor(s, 8);
            float is = 1.0f / s;
            ph[ti][0][r] = (half_t)(e0 * is);
            ph[ti][1][r] = (half_t)(e1 * is);
            ph[ti][2][r] = (half_t)(e2 * is);
            ph[ti][3][r] = (half_t)(e3 * is);
        }
    }

    half4 vh[2][4];
    {
        float4v va[2][4];
        #pragma unroll
        for (int c2 = 0; c2 < 2; ++c2)
            #pragma unroll
            for (int ti = 0; ti < 4; ++ti) va[c2][ti] = {0.f, 0.f, 0.f, 0.f};
        const half_t* wvb = wqkvT + (size_t)(512 + w * 32 + m) * 256 + g * 8;
        #pragma unroll
        for (int kk = 0; kk < 8; ++kk) {
            half8 wv0 = *(const half8*)(wvb + kk * 32);
            half8 wv1 = *(const half8*)(wvb + 16 * 256 + kk * 32);
            #pragma unroll
            for (int ti = 0; ti < 4; ++ti) {
                half8 af = *(const half8*)(xs + swzA(ti * 16 + m, kk * 64 + g * 16));
                va[0][ti] = mfma16(af, wv0, va[0][ti]);
                va[1][ti] = mfma16(af, wv1, va[1][ti]);
            }
        }
        float vb0 = qkv_b[512 + w * 32 + m], vb1 = qkv_b[512 + w * 32 + 16 + m];
        #pragma unroll
        for (int c2 = 0; c2 < 2; ++c2)
            #pragma unroll
            for (int ti = 0; ti < 4; ++ti)
                #pragma unroll
                for (int r = 0; r < 4; ++r)
                    vh[c2][ti][r] = (half_t)(va[c2][ti][r] + (c2 ? vb1 : vb0));
    }
    __syncthreads();

    #pragma unroll
    for (int c2 = 0; c2 < 2; ++c2)
        #pragma unroll
        for (int ti = 0; ti < 4; ++ti)
            *(half4*)(vts + swzC(c2 * 16 + m, ti * 32 + g * 8)) = vh[c2][ti];

    float4v oacc[2][4];
    #pragma unroll
    for (int tjd = 0; tjd < 2; ++tjd)
        #pragma unroll
        for (int ti = 0; ti < 4; ++ti) oacc[tjd][ti] = {0.f, 0.f, 0.f, 0.f};
    #pragma unroll
    for (int nc = 0; nc < 2; ++nc) {
        #pragma unroll
        for (int ti = 0; ti < 4; ++ti)
            #pragma unroll
            for (int t2 = 0; t2 < 2; ++t2)
                #pragma unroll
                for (int r = 0; r < 4; ++r)
                    *(half_t*)(wA + swzB(ti * 16 + g * 4 + r, (t2 * 16 + m) * 2)) =
                        ph[ti][nc * 2 + t2][r];
        half8 pa[4];
        #pragma unroll
        for (int ti = 0; ti < 4; ++ti)
            pa[ti] = *(const half8*)(wA + swzB(ti * 16 + m, g * 16));
        #pragma unroll
        for (int tjd = 0; tjd < 2; ++tjd) {
            half8 bv = *(const half8*)(vts + swzC(tjd * 16 + m, nc * 64 + g * 16));
            #pragma unroll
            for (int ti = 0; ti < 4; ++ti)
                oacc[tjd][ti] = mfma16(pa[ti], bv, oacc[tjd][ti]);
        }
        __builtin_amdgcn_sched_barrier(0);
    }
    __syncthreads();

    #pragma unroll
    for (int tjd = 0; tjd < 2; ++tjd)
        #pragma unroll
        for (int ti = 0; ti < 4; ++ti)
            #pragma unroll
            for (int r = 0; r < 4; ++r)
                *(half_t*)(atn + swzA(ti * 16 + g * 4 + r, (w * 32 + tjd * 16 + m) * 2)) =
                    (half_t)oacc[tjd][ti][r];
    __syncthreads();

    float* og = out + (size_t)b * 16384;
    const int oc0 = w * 32;
    float4v pacc[2][4];
    #pragma unroll
    for (int c2 = 0; c2 < 2; ++c2)
        #pragma unroll
        for (int ti = 0; ti < 4; ++ti) pacc[c2][ti] = {0.f, 0.f, 0.f, 0.f};
    const half_t* wpb = wprojT + (size_t)(oc0 + m) * 256 + g * 8;
    #pragma unroll
    for (int kk = 0; kk < 8; ++kk) {
        half8 wf0 = *(const half8*)(wpb + kk * 32);
        half8 wf1 = *(const half8*)(wpb + 16 * 256 + kk * 32);
        #pragma unroll
        for (int ti = 0; ti < 4; ++ti) {
            half8 af = *(const half8*)(atn + swzA(ti * 16 + m, kk * 64 + g * 16));
            pacc[0][ti] = mfma16(af, wf0, pacc[0][ti]);
            pacc[1][ti] = mfma16(af, wf1, pacc[1][ti]);
        }
    }
    float pb0 = proj_b[oc0 + m], pb1 = proj_b[oc0 + 16 + m];
    #pragma unroll
    for (int c2 = 0; c2 < 2; ++c2)
        #pragma unroll
        for (int ti = 0; ti < 4; ++ti)
            #pragma unroll
            for (int r = 0; r < 4; ++r)
                og[(ti * 16 + g * 4 + r) * 256 + oc0 + c2 * 16 + m] =
                    pacc[c2][ti][r] + (c2 ? pb1 : pb0);
}

extern "C" void kernel_launch(void* const* d_in, const int* in_sizes, int n_in,
                              void* d_out, int out_size, void* d_ws, size_t ws_size,
                              hipStream_t stream) {
    const float* x          = (const float*)d_in[0];
    const float* qkv_w      = (const float*)d_in[1];
    const float* qkv_b      = (const float*)d_in[2];
    const float* proj_w     = (const float*)d_in[3];
    const float* proj_b     = (const float*)d_in[4];
    const float* pos_proj_w = (const float*)d_in[5];
    const float* pos_proj_b = (const float*)d_in[6];
    const float* ln1_g = (const float*)d_in[7];
    const float* ln1_b = (const float*)d_in[8];
    const float* fc1_w = (const float*)d_in[9];
    const float* fc1_b = (const float*)d_in[10];
    const float* ln2_g = (const float*)d_in[11];
    const float* ln2_b = (const float*)d_in[12];
    const float* fc2_w = (const float*)d_in[13];
    const float* fc2_b = (const float*)d_in[14];
    const float* ln3_g = (const float*)d_in[15];
    const float* ln3_b = (const float*)d_in[16];
    const float* fc3_w = (const float*)d_in[17];
    const float* fc3_b = (const float*)d_in[18];
    const float* biases = (const float*)d_in[19];
    const int*  rel_idx = (const int*)d_in[20];

    half_t* wqkvT  = (half_t*)d_ws;
    half_t* wprojT = (half_t*)((char*)d_ws + 393216);
    float*  rbp    = (float*)((char*)d_ws + 524288);

    const int B = in_sizes[0] / (64 * 256);
    // intermediates: q,k (fp16 row-major) live in d_out (exact fit, dead by
    // proj); vT + attn live in ws.
    half_t* q_ws    = (half_t*)d_out;
    half_t* k_ws    = q_ws + (size_t)B * 16384;
    half_t* vt_ws   = (half_t*)((char*)d_ws + 655360);
    half_t* attn_ws = vt_ws + (size_t)B * 16384;
    const size_t need = 655360 + (size_t)B * 65536;

    prep_kernel<<<65, 256, 0, stream>>>(qkv_w, proj_w, biases, pos_proj_w, pos_proj_b,
                                        ln1_g, ln1_b, fc1_w, fc1_b,
                                        ln2_g, ln2_b, fc2_w, fc2_b,
                                        ln3_g, ln3_b, fc3_w, fc3_b,
                                        rel_idx, wqkvT, wprojT, rbp);
    if (ws_size >= need) {
        qkv_gemm_kernel<<<B, 256, 0, stream>>>(x, wqkvT, qkv_b, q_ws, k_ws, vt_ws);
        attn_kernel<<<B * 2, 256, 0, stream>>>(q_ws, k_ws, vt_ws, rbp, attn_ws);
        proj_kernel<<<B, 256, 0, stream>>>(attn_ws, wprojT, proj_b, (float*)d_out);
    } else {
        fused_fallback<<<B, 512, 0, stream>>>(x, wqkvT, qkv_b, wprojT, proj_b, rbp,
                                              (float*)d_out);
    }
}